// Round 20
// baseline (140.793 us; speedup 1.0000x reference)
//
#include <hip/hip_runtime.h>
#include <hip/hip_fp16.h>

// Problem constants
#define BB 4
#define TT 16
#define HH 512
#define WW 512
#define SP 528                        // padded row stride (halfs) of the f16 inter-pass buffer

// 512 threads = 8 waves; output 64x64. Wave (rs,chf): rows 16rs..16rs+15,
// cols 32chf..32chf+31 (2 MFMA col strips -> 2 acc chains).
// LDS: 2 ping-pong channel planes + resident copy of all 27 B-fragments.
#define BTILE 64
#define ROWB 160                      // plane row stride bytes (80 halfs)
#define PROWS 80                      // 64 + 2*8 halo
#define PLANE_BYTES (PROWS * ROWB)    // 12800
#define BLDS_OFF (2 * PLANE_BYTES)    // 25600
#define BFRAG_BYTES 27648             // 27 mats x 64 lanes x 16 B
#define LDS_BYTES (BLDS_OFF + BFRAG_BYTES)   // 53248 -> 3 blocks/CU, 24 waves/CU

typedef _Float16 half8 __attribute__((ext_vector_type(8)));
typedef float f32x4 __attribute__((ext_vector_type(4)));

constexpr int kR[9] = {-8, -4, -2, -1, 0, 1, 2, 4, 8};   // merged tap rows

__device__ __forceinline__ int reflect_idx(int q, int n) {
    q = abs(q);
    if (q >= n) q = 2 * n - 2 - q;
    return q;
}

__device__ __forceinline__ void async_cp16(const void* g, char* l) {
#if __has_builtin(__builtin_amdgcn_global_load_lds)
    __builtin_amdgcn_global_load_lds(
        (const __attribute__((address_space(1))) unsigned int*)g,
        (__attribute__((address_space(3))) unsigned int*)l, 16, 0, 0);
#else
    *reinterpret_cast<uint4*>(l) = *reinterpret_cast<const uint4*>(g);
#endif
}

// 27 B-fragment matrices (ch x tap-row), 32x16 f16 banded-Toeplitz in MFMA fragment order:
// frag[(ch*9+ri)*64 + lane][e], B[k][j], j=lane&15, k=8*(lane>>4)+e, val=merged_w[ch][r][k-8-j].
// Combined bias stored as float at halfs[27*64*8].
__global__ void pack_bfrag(const float* __restrict__ w1, const float* __restrict__ b1,
                           const float* __restrict__ w2, const float* __restrict__ b2,
                           const float* __restrict__ w3, const float* __restrict__ b3,
                           const float* __restrict__ sa, const float* __restrict__ sb,
                           const float* __restrict__ sc_, __half* __restrict__ bfrag) {
    const int tid = threadIdx.x;
    float s[3] = {sa[0], sb[0], sc_[0]};
    const float* wp[3] = {w1, w2, w3};
    for (int idx = tid; idx < 27 * 64; idx += blockDim.x) {
        int mat = idx >> 6;
        int lane = idx & 63;
        int ch = mat / 9, ri = mat % 9;
        int r = kR[ri];
        int j = lane & 15, kg = lane >> 4;
        union { __half h[8]; uint4 u; } v;
#pragma unroll
        for (int e = 0; e < 8; ++e) {
            int k = kg * 8 + e;
            int c = k - 8 - j;
            float a = 0.f;
            if (c >= -8 && c <= 8) {
                for (int b = 0; b < 3; ++b) {
                    int d = 1 << b;
                    if (r % d == 0 && c % d == 0) {
                        int rd = r / d, cd = c / d;
                        if (rd >= -2 && rd <= 2 && cd >= -2 && cd <= 2)
                            a += s[b] * wp[b][ch * 25 + (rd + 2) * 5 + (cd + 2)];
                    }
                }
            }
            v.h[e] = __float2half(a);
        }
        *reinterpret_cast<uint4*>(bfrag + idx * 8) = v.u;
    }
    if (tid == 0)
        *reinterpret_cast<float*>(bfrag + 27 * 64 * 8) = s[0] * b1[0] + s[1] * b2[0] + s[2] * b3[0];
}

// ---- STAGE helpers: static control flow, named src pointers ----
__device__ __forceinline__ void stage_f32(const float* __restrict__ src, char* buf,
                                          int h0, int w0, int tid) {
    for (int k2 = tid; k2 < PROWS * 10; k2 += 512) {
        int row = k2 / 10;
        int c8  = k2 - row * 10;
        int gh = reflect_idx(h0 - 8 + row, HH);
        int gb = w0 - 8 + c8 * 8;
        const float* rp = src + (size_t)gh * WW;
        union { __half2 h2[4]; uint4 u; } cv;
        if (gb >= 0 && gb + 7 < WW) {
            const float4 v0 = *reinterpret_cast<const float4*>(rp + gb);
            const float4 v1 = *reinterpret_cast<const float4*>(rp + gb + 4);
            cv.h2[0] = __floats2half2_rn(v0.x, v0.y);
            cv.h2[1] = __floats2half2_rn(v0.z, v0.w);
            cv.h2[2] = __floats2half2_rn(v1.x, v1.y);
            cv.h2[3] = __floats2half2_rn(v1.z, v1.w);
        } else {
#pragma unroll
            for (int e = 0; e < 4; ++e)
                cv.h2[e] = __floats2half2_rn(rp[reflect_idx(gb + 2 * e, WW)],
                                             rp[reflect_idx(gb + 2 * e + 1, WW)]);
        }
        *reinterpret_cast<uint4*>(buf + row * ROWB + c8 * 16) = cv.u;
    }
}

__device__ __forceinline__ void stage_f16(const __half* __restrict__ src, char* buf,
                                          int h0, int w0, int wv, int lane) {
#pragma unroll
    for (int c0 = 0; c0 < 2; ++c0) {               // 13 chunks over 8 waves
        int c = c0 * 8 + wv;
        if (c < 13) {
            int byt = c * 1024 + lane * 16;
            if (byt < PLANE_BYTES) {               // tail of chunk 12 masked
                int row  = byt / ROWB;
                int colh = (byt - row * ROWB) >> 1;
                int gh = reflect_idx(h0 - 8 + row, HH);
                async_cp16(src + (size_t)gh * SP + (w0 + colh), buf + byt);
            }
        }
    }
}

// PASS 1: in = f32 x (unpadded), out = f16 ypad (stride SP, reflect-padded cols)
// PASS 2: in = f16 ypad,         out = f32 z   (unpadded)
template <int PASS>
__global__ __launch_bounds__(512, 6) void conv_mfma(const void* __restrict__ xin,
                                                    void* __restrict__ outp,
                                                    const __half* __restrict__ bfrag) {
    __shared__ char lds[LDS_BYTES];

    const int bt = blockIdx.z;
    const int t  = bt % TT;
    const int h0 = blockIdx.y * BTILE;
    const int w0 = blockIdx.x * BTILE;
    const int tid = threadIdx.x;
    const int lane = tid & 63;
    const int wv = tid >> 6;                  // 0..7
    const int rs  = wv >> 1;                  // row strip 0..3
    const int chf = wv & 1;                   // col half 0..1

    char* buf0 = lds;
    char* buf1 = lds + PLANE_BYTES;
    char* ldsB = lds + BLDS_OFF;

    const int tprev = (t == 0) ? 1 : t - 1;
    const int tnext = (t == TT - 1) ? TT - 2 : t + 1;
    const int bbase = (bt / TT) * TT;

    // Named frame pointers (no arrays -> no scratch)
    const float *xf0 = nullptr, *xf1 = nullptr, *xf2 = nullptr;
    const __half *yf0 = nullptr, *yf1 = nullptr, *yf2 = nullptr;
    if constexpr (PASS == 1) {
        const float* x = (const float*)xin;
        const size_t fs = (size_t)HH * WW;
        xf0 = x + (size_t)(bbase + tprev) * fs;
        xf1 = x + (size_t)bt * fs;
        xf2 = x + (size_t)(bbase + tnext) * fs;
    } else {
        const __half* y = (const __half*)xin;
        const size_t fsP = (size_t)HH * SP;
        yf0 = y + (size_t)(bbase + tprev) * fsP;
        yf1 = y + (size_t)bt * fsP;
        yf2 = y + (size_t)(bbase + tnext) * fsP;
    }

    // ---- One-time cooperative DMA: all 27 B-fragments global -> LDS ----
#pragma unroll
    for (int c0 = 0; c0 < 4; ++c0) {               // 27 x 1024B chunks over 8 waves
        int c = c0 * 8 + wv;
        if (c < 27)
            async_cp16((const char*)bfrag + c * 1024 + lane * 16, ldsB + c * 1024 + lane * 16);
    }

    const float bias = *reinterpret_cast<const float*>(bfrag + 27 * 64 * 8);
    f32x4 acc0 = {bias, bias, bias, bias};
    f32x4 acc1 = acc0;

    const int i16 = lane & 15;
    const int kg  = lane >> 4;
    const int aoff = (16 * rs + i16) * ROWB + kg * 16 + chf * 64;
    const char* bB = ldsB + lane * 16;             // + (ch*9+ri)*1024 literal

#define STAGE_CH(CH, BUF)                                                        \
    do {                                                                         \
        if constexpr (PASS == 1)                                                 \
            stage_f32((CH) == 0 ? xf0 : (CH) == 1 ? xf1 : xf2, BUF, h0, w0, tid);\
        else                                                                     \
            stage_f16((CH) == 0 ? yf0 : (CH) == 1 ? yf1 : yf2, BUF, h0, w0, wv, lane); \
    } while (0)

#define COMPUTE_CH(CH, BUF)                                                      \
    do {                                                                         \
        const char* aB = (BUF) + aoff;                                           \
        _Pragma("unroll")                                                        \
        for (int ri = 0; ri < 9; ++ri) {                                         \
            const half8 b = *reinterpret_cast<const half8*>(bB + ((CH) * 9 + ri) * 1024); \
            const char* ar = aB + (kR[ri] + 8) * ROWB;                           \
            half8 a0 = *reinterpret_cast<const half8*>(ar);                      \
            half8 a1 = *reinterpret_cast<const half8*>(ar + 32);                 \
            __builtin_amdgcn_s_setprio(1);                                       \
            acc0 = __builtin_amdgcn_mfma_f32_16x16x32_f16(a0, b, acc0, 0, 0, 0); \
            acc1 = __builtin_amdgcn_mfma_f32_16x16x32_f16(a1, b, acc1, 0, 0, 0); \
            __builtin_amdgcn_s_setprio(0);                                       \
        }                                                                        \
    } while (0)

    // ---- proven ping-pong schedule (r14/r18), channels fully unrolled ----
    STAGE_CH(0, buf0);
    asm volatile("s_waitcnt vmcnt(0)" ::: "memory");   // B-DMA (+stage DMA in pass 2)
    __syncthreads();
    STAGE_CH(1, buf1);
    COMPUTE_CH(0, buf0);

    if constexpr (PASS == 2) asm volatile("s_waitcnt vmcnt(0)" ::: "memory");
    __syncthreads();
    STAGE_CH(2, buf0);
    COMPUTE_CH(1, buf1);

    if constexpr (PASS == 2) asm volatile("s_waitcnt vmcnt(0)" ::: "memory");
    __syncthreads();
    COMPUTE_CH(2, buf0);

#undef STAGE_CH
#undef COMPUTE_CH

    // ---- Epilogue: tanh; C layout col=lane&15, row=(lane>>4)*4+reg ----
    if constexpr (PASS == 1) {
        __half* yp = (__half*)outp + (size_t)bt * HH * SP;
#pragma unroll
        for (int sc = 0; sc < 2; ++sc) {
            f32x4 a = (sc == 0) ? acc0 : acc1;
            const int wcol = w0 + chf * 32 + sc * 16 + i16;
#pragma unroll
            for (int v2 = 0; v2 < 4; ++v2) {
                float z = a[v2];
                float e = __expf(2.0f * z);
                z = 1.0f - 2.0f / (e + 1.0f);
                __half hz = __float2half(z);
                __half* rb = yp + (size_t)(h0 + 16 * rs + kg * 4 + v2) * SP;
                rb[8 + wcol] = hz;
                if (wcol >= 1 && wcol <= 8)          rb[8 - wcol] = hz;       // left mirror
                else if (wcol >= 503 && wcol <= 510) rb[1030 - wcol] = hz;    // right mirror
            }
        }
    } else {
        float* dst = (float*)outp + (size_t)bt * HH * WW
                   + (size_t)(h0 + 16 * rs + kg * 4) * WW + (w0 + chf * 32 + i16);
#pragma unroll
        for (int sc = 0; sc < 2; ++sc) {
            f32x4 a = (sc == 0) ? acc0 : acc1;
#pragma unroll
            for (int v2 = 0; v2 < 4; ++v2) {
                float z = a[v2];
                float e = __expf(2.0f * z);
                dst[(size_t)v2 * WW + sc * 16] = 1.0f - 2.0f / (e + 1.0f);
            }
        }
    }
}

extern "C" void kernel_launch(void* const* d_in, const int* in_sizes, int n_in,
                              void* d_out, int out_size, void* d_ws, size_t ws_size,
                              hipStream_t stream) {
    const float* x = (const float*)d_in[0];
    char* ws = (char*)d_ws;
    __half* bf1  = (__half*)ws;                        // 27.7 KB
    __half* bf2  = (__half*)(ws + 32768);              // 27.7 KB
    __half* ypad = (__half*)(ws + 65536);              // 64 x 512 x 528 f16 = 34.6 MB

    pack_bfrag<<<1, 256, 0, stream>>>((const float*)d_in[1], (const float*)d_in[2],
                                      (const float*)d_in[3], (const float*)d_in[4],
                                      (const float*)d_in[5], (const float*)d_in[6],
                                      (const float*)d_in[7], (const float*)d_in[8],
                                      (const float*)d_in[9], bf1);
    pack_bfrag<<<1, 256, 0, stream>>>((const float*)d_in[10], (const float*)d_in[11],
                                      (const float*)d_in[12], (const float*)d_in[13],
                                      (const float*)d_in[14], (const float*)d_in[15],
                                      (const float*)d_in[16], (const float*)d_in[17],
                                      (const float*)d_in[18], bf2);

    dim3 grid(WW / BTILE, HH / BTILE, BB * TT);   // 8 x 8 x 64
    conv_mfma<1><<<grid, 512, 0, stream>>>(x, ypad, bf1);
    conv_mfma<2><<<grid, 512, 0, stream>>>(ypad, d_out, bf2);
}